// Round 5
// baseline (353.135 us; speedup 1.0000x reference)
//
#include <hip/hip_runtime.h>
#include <hip/hip_bf16.h>

typedef unsigned short u16;
typedef __attribute__((ext_vector_type(8))) short short8;
typedef __attribute__((ext_vector_type(4))) float f32x4;
typedef __attribute__((ext_vector_type(4))) float float4v;
typedef __attribute__((ext_vector_type(4))) unsigned short us4;
typedef __attribute__((ext_vector_type(2))) unsigned int uint2v;

#define NN       100000
#define OFF_WK   16384
#define OFF_WV   98304
#define OFF_W1   180224     // combined W1/W2 region: [c][kb2][W1 4096 u16][W2 4096 u16]
#define PACK_ELEMS 311296

// ws byte offsets
#define WS_LWS   0u
#define WS_PM    8000000u
#define WS_PS    8000640u
#define WS_MHR   8001280u
#define WS_ISHR  8001408u
#define WS_PK    8001536u
#define WS_XB    8624128u          // 12.8M u16 = 25,600,000 B
#define WS_SV    34224128u         // 1152 u16 small vectors

// per-wave LDS scratch: 32 rows x pitch 36 u16 (pad kills 16-way bank conflicts)
#define PWS_PITCH 36
#define PWS_SLICE 1280             // u16 per wave (2560 B, >= 32*36=1152 u16; aligns with attw slice)

static __device__ __forceinline__ float b2f(u16 u){
  unsigned int i = ((unsigned int)u) << 16;
  float f; __builtin_memcpy(&f, &i, 4); return f;
}
static __device__ __forceinline__ u16 f2b(float f){
  unsigned int i; __builtin_memcpy(&i, &f, 4);
  i += 0x7FFFu + ((i >> 16) & 1u);
  return (u16)(i >> 16);
}
static __device__ __forceinline__ f32x4 mfma16(short8 a, short8 b, f32x4 c){
  return __builtin_amdgcn_mfma_f32_16x16x32_bf16(a, b, c, 0, 0, 0);
}
static __device__ __forceinline__ bool detect32(const void* g1){
  return ((const u16*)g1)[0] == 0;
}
static __device__ __forceinline__ float ldf(const void* p, size_t i, bool is32){
  return is32 ? ((const float*)p)[i] : b2f(((const u16*)p)[i]);
}
// 8B-aligned LDS A-frag read (two ds_read_b64; pitch-36 rows are not 16B aligned)
static __device__ __forceinline__ short8 lds_afrag(const u16* p){
  uint2v a = *(const uint2v*)p;
  uint2v b = *(const uint2v*)(p + 4);
  short8 r;
  unsigned int* rp = (unsigned int*)&r;
  rp[0] = a.x; rp[1] = a.y; rp[2] = b.x; rp[3] = b.y;
  return r;
}

// ---------- canonicalize x to bf16 ----------
__global__ __launch_bounds__(256) void k_convert_x(
    const void* __restrict__ x, const void* __restrict__ g1, u16* __restrict__ xb)
{
  const bool is32 = detect32(g1);
  size_t i = (size_t)blockIdx.x * 256 + threadIdx.x;   // 4 elems each
  us4 o;
  if (is32){
    float4v v = ((const float4v*)x)[i];
    o.x = f2b(v.x); o.y = f2b(v.y); o.z = f2b(v.z); o.w = f2b(v.w);
  } else {
    o = ((const us4*)x)[i];
  }
  ((us4*)xb)[i] = o;
}

// ---------- canonicalize small vectors ----------
__global__ __launch_bounds__(256) void k_convert_small(
    const void* b1, const void* b2, const void* g1, const void* be1,
    const void* g2, const void* be2, u16* __restrict__ sv)
{
  const bool is32 = detect32(g1);
  for (int i = threadIdx.x; i < 1152; i += 256){
    const void* src; int off;
    if      (i < 512) { src = b1;  off = i; }
    else if (i < 640) { src = b2;  off = i - 512; }
    else if (i < 768) { src = g1;  off = i - 640; }
    else if (i < 896) { src = be1; off = i - 768; }
    else if (i < 1024){ src = g2;  off = i - 896; }
    else              { src = be2; off = i - 1024; }
    sv[i] = f2b(ldf(src, off, is32));
  }
}

// ---------- weight repack into MFMA-B-fragment order ----------
// Wq/Wk/Wv: packed[t][kb][lane][j] = B[kb*32+(lane>>4)*8+j][t*16+(lane&15)]
// W1/W2 combined region at OFF_W1: per (c,kb2) an 8192-u16 block:
//   first 4096: W1 frag [u][kb][lane][j]  (cols c*128+(kb2*2+u)*16+m, rows kb*32+..)
//   next  4096: W2 frag [t][lane][j]      (rows (c*4+kb2)*32+.., cols t*16+m)
__global__ __launch_bounds__(256) void k_pack(
    const void* __restrict__ wq, const void* __restrict__ wk,
    const void* __restrict__ wv, const void* __restrict__ W1,
    const void* __restrict__ W2, const void* __restrict__ g1,
    u16* __restrict__ pk)
{
  const bool is32 = detect32(g1);
  int p = blockIdx.x * 256 + threadIdx.x;
  if (p >= PACK_ELEMS) return;
  float v;
  if (p < OFF_WK){                       // Wq
    int q = p;
    int j = q & 7, lane = (q >> 3) & 63, tk = q >> 9;
    int kb = tk & 3, t = tk >> 2;
    int kd = kb*32 + (lane>>4)*8 + j, nc = t*16 + (lane & 15);
    v = ldf(wq, (size_t)(nc>>5)*4096 + kd*32 + (nc & 31), is32);
  } else if (p < OFF_WV){                // Wk[r]
    int q = p - OFF_WK; int r = q >> 14; q &= 16383;
    int j = q & 7, lane = (q >> 3) & 63, tk = q >> 9;
    int kb = tk & 3, t = tk >> 2;
    int kd = kb*32 + (lane>>4)*8 + j, nc = t*16 + (lane & 15);
    v = ldf(wk, (size_t)((nc>>5)*5 + r)*4096 + kd*32 + (nc & 31), is32);
  } else if (p < OFF_W1){                // Wv[r]
    int q = p - OFF_WV; int r = q >> 14; q &= 16383;
    int j = q & 7, lane = (q >> 3) & 63, tk = q >> 9;
    int kb = tk & 3, t = tk >> 2;
    int kd = kb*32 + (lane>>4)*8 + j, nc = t*16 + (lane & 15);
    v = ldf(wv, (size_t)((nc>>5)*5 + r)*4096 + kd*32 + (nc & 31), is32);
  } else {                               // W1/W2 interleaved per (c,kb2)
    int q = p - OFF_W1;
    int j = q & 7, lane = (q >> 3) & 63, rest = q >> 9;   // [0,256)
    int pairIdx = rest >> 4, sub = rest & 15;
    int c = pairIdx >> 2, kb2 = pairIdx & 3;
    int half = lane >> 4, mc = lane & 15;
    if (sub < 8){                        // W1 frag [u][kb]
      int u = sub >> 2, kb = sub & 3;
      int kd = kb*32 + half*8 + j;
      int nc = c*128 + (kb2*2+u)*16 + mc;
      v = ldf(W1, (size_t)kd*512 + nc, is32);
    } else {                             // W2 frag [t]
      int t = sub - 8;
      int kd = (c*4+kb2)*32 + half*8 + j;
      int nc = t*16 + mc;
      v = ldf(W2, (size_t)kd*128 + nc, is32);
    }
  }
  pk[p] = f2b(v);
}

// ---------- phase 1: Q, K, logits — 4 waves x M=32, LDS-staged W ----------
__global__ __launch_bounds__(256, 3) void k_qk(
    const u16* __restrict__ x, const int* __restrict__ nbr,
    const u16* __restrict__ pw, float* __restrict__ lws)
{
  __shared__ __align__(16) u16 sbuf[16384];   // 32 KB weight stage
  const int tid = threadIdx.x, lane = tid & 63, wv = tid >> 6;
  const int m = lane & 15, quad = lane >> 4;
  const int n0 = blockIdx.x * 128 + wv * 32;
  const bool act0 = (n0 < NN), act1 = (n0 + 16 < NN);

  const short8* sb8 = (const short8*)sbuf;
  // stage Wq
  for (int s = tid; s < 2048; s += 256)
    ((short8*)sbuf)[s] = ((const short8*)pw)[s];
  __syncthreads();

  short8 a[2][4];
  f32x4 q[2][8];
  #pragma unroll
  for (int tl = 0; tl < 2; tl++)
    #pragma unroll
    for (int t = 0; t < 8; t++) q[tl][t] = (f32x4){0.f,0.f,0.f,0.f};

  #pragma unroll
  for (int tl = 0; tl < 2; tl++){
    if (!(tl ? act1 : act0)) continue;
    const short8* xp = (const short8*)(x + (size_t)(n0 + tl*16 + m) * 128);
    #pragma unroll
    for (int kb = 0; kb < 4; kb++) a[tl][kb] = xp[kb*4 + quad];
  }
  #pragma unroll
  for (int t = 0; t < 8; t++){
    short8 bfr[4];
    #pragma unroll
    for (int kb = 0; kb < 4; kb++) bfr[kb] = sb8[(t*4+kb)*64 + lane];
    #pragma unroll
    for (int tl = 0; tl < 2; tl++){
      if (!(tl ? act1 : act0)) continue;
      #pragma unroll
      for (int kb = 0; kb < 4; kb++) q[tl][t] = mfma16(a[tl][kb], bfr[kb], q[tl][t]);
    }
  }

  for (int r = 0; r < 5; r++){
    __syncthreads();
    for (int s = tid; s < 2048; s += 256)
      ((short8*)sbuf)[s] = ((const short8*)(pw + OFF_WK + (size_t)r*16384))[s];
    __syncthreads();
    if (r > 0){
      #pragma unroll
      for (int tl = 0; tl < 2; tl++){
        if (!(tl ? act1 : act0)) continue;
        int node = nbr[(size_t)(n0 + tl*16 + m)*4 + (r-1)];
        const short8* xp = (const short8*)(x + (size_t)node * 128);
        #pragma unroll
        for (int kb = 0; kb < 4; kb++) a[tl][kb] = xp[kb*4 + quad];
      }
    }
    #pragma unroll
    for (int h = 0; h < 4; h++){
      short8 b0[4], b1f[4];
      #pragma unroll
      for (int kb = 0; kb < 4; kb++){
        b0[kb]  = sb8[((2*h  )*4+kb)*64 + lane];
        b1f[kb] = sb8[((2*h+1)*4+kb)*64 + lane];
      }
      #pragma unroll
      for (int tl = 0; tl < 2; tl++){
        if (!(tl ? act1 : act0)) continue;
        f32x4 k0 = {0.f,0.f,0.f,0.f}, k1 = {0.f,0.f,0.f,0.f};
        #pragma unroll
        for (int kb = 0; kb < 4; kb++){
          k0 = mfma16(a[tl][kb], b0[kb],  k0);
          k1 = mfma16(a[tl][kb], b1f[kb], k1);
        }
        float p[4];
        #pragma unroll
        for (int i = 0; i < 4; i++) p[i] = q[tl][2*h][i]*k0[i] + q[tl][2*h+1][i]*k1[i];
        #pragma unroll
        for (int mask = 1; mask < 16; mask <<= 1){
          #pragma unroll
          for (int i = 0; i < 4; i++) p[i] += __shfl_xor(p[i], mask, 16);
        }
        if (m == 0){
          #pragma unroll
          for (int i = 0; i < 4; i++)
            lws[(size_t)(h*5+r)*NN + n0 + tl*16 + quad*4 + i]
                = p[i] * 0.17677669529663687f;
        }
      }
    }
  }
}

// ---------- phase 2a: per-(h,r) partial max / sumexp ----------
__global__ __launch_bounds__(256) void k_red_part(
    const float* __restrict__ lws, float* __restrict__ pm, float* __restrict__ ps)
{
  const int hr = blockIdx.x >> 3, pb = blockIdx.x & 7;
  const int start = pb * 12500, end = start + 12500;
  const float* v = lws + (size_t)hr * NN;
  __shared__ float red[256];
  float mx = -1e30f;
  for (int i = start + threadIdx.x; i < end; i += 256) mx = fmaxf(mx, v[i]);
  red[threadIdx.x] = mx; __syncthreads();
  for (int s = 128; s > 0; s >>= 1){
    if ((int)threadIdx.x < s) red[threadIdx.x] = fmaxf(red[threadIdx.x], red[threadIdx.x+s]);
    __syncthreads();
  }
  mx = red[0]; __syncthreads();
  float sm = 0.f;
  for (int i = start + threadIdx.x; i < end; i += 256) sm += __expf(v[i] - mx);
  red[threadIdx.x] = sm; __syncthreads();
  for (int s = 128; s > 0; s >>= 1){
    if ((int)threadIdx.x < s) red[threadIdx.x] += red[threadIdx.x+s];
    __syncthreads();
  }
  if (threadIdx.x == 0){ pm[blockIdx.x] = mx; ps[blockIdx.x] = red[0]; }
}

__global__ __launch_bounds__(64) void k_red_fin(
    const float* __restrict__ pm, const float* __restrict__ ps,
    float* __restrict__ mhr, float* __restrict__ ishr)
{
  int t = threadIdx.x;
  if (t < 20){
    float M = -1e30f;
    for (int b = 0; b < 8; b++) M = fmaxf(M, pm[t*8+b]);
    float S = 0.f;
    for (int b = 0; b < 8; b++) S += ps[t*8+b] * __expf(pm[t*8+b] - M);
    mhr[t] = M; ishr[t] = 1.0f / S;
  }
}

// ---------- phase 3: V, combine, LN1, FFN, LN2 ----------
// 4 waves x M=32; barriers ONLY around sbuf weight stages; per-wave padded
// scratch (overlaid with per-wave attw) for the D->A fragment transforms.
__global__ __launch_bounds__(256, 3) void k_attn_ffn(
    const u16* __restrict__ x, const void* __restrict__ xraw,
    const int* __restrict__ nbr,
    const u16* __restrict__ pw, const float* __restrict__ lws,
    const float* __restrict__ mhr, const float* __restrict__ ishr,
    const u16* __restrict__ sv, const void* __restrict__ g1raw,
    float* __restrict__ out)
{
  __shared__ __align__(16) u16 sbuf[16384];    // 32 KB weight stage
  __shared__ __align__(16) u16 upool[5120];    // 10 KB: per-wave attw (V) / pws (FFN)
  const int tid = threadIdx.x, lane = tid & 63, wv = tid >> 6;
  const int m = lane & 15, quad = lane >> 4;
  const int n0 = blockIdx.x * 128 + wv * 32;
  const bool act0 = (n0 < NN), act1 = (n0 + 16 < NN);
  const bool is32 = detect32(g1raw);
  const u16* b1s = sv;
  const u16* b2s = sv + 512;
  const u16* g1s = sv + 640;
  const u16* be1s = sv + 768;
  const u16* g2s = sv + 896;
  const u16* be2s = sv + 1024;
  const short8* sb8 = (const short8*)sbuf;
  float* attw_w = ((float*)upool) + wv * 640;        // this wave's 2 tiles x 320
  u16*   pws_w  = upool + wv * PWS_SLICE;            // same bytes, reused post-V

  // per-wave attention weights (no cross-wave access -> no barrier needed)
  for (int j = lane; j < 640; j += 64){
    int tl = j / 320, rem = j - tl*320;
    int r = rem >> 6, h = (rem >> 4) & 3, mm = rem & 15, hr = h*5 + r;
    int node = n0 + tl*16 + mm;
    attw_w[j] = (node < NN)
        ? __expf(lws[(size_t)hr*NN + node] - mhr[hr]) * ishr[hr] : 0.f;
  }

  // ---------------- V phase ----------------
  f32x4 zacc[2][8];
  #pragma unroll
  for (int tl = 0; tl < 2; tl++)
    #pragma unroll
    for (int t = 0; t < 8; t++) zacc[tl][t] = (f32x4){0.f,0.f,0.f,0.f};

  short8 a2[2][4];
  for (int r = 0; r < 5; r++){
    __syncthreads();
    for (int s = tid; s < 2048; s += 256)
      ((short8*)sbuf)[s] = ((const short8*)(pw + OFF_WV + (size_t)r*16384))[s];
    __syncthreads();

    #pragma unroll
    for (int tl = 0; tl < 2; tl++){
      if (!(tl ? act1 : act0)) continue;
      int rowb = n0 + tl*16;
      const short8* xp;
      if (r == 0) xp = (const short8*)(x + (size_t)(rowb + m) * 128);
      else {
        int node = nbr[(size_t)(rowb + m)*4 + (r-1)];
        xp = (const short8*)(x + (size_t)node * 128);
      }
      #pragma unroll
      for (int kb = 0; kb < 4; kb++) a2[tl][kb] = xp[kb*4 + quad];
    }
    #pragma unroll
    for (int t = 0; t < 8; t++){
      short8 bfr[4];
      #pragma unroll
      for (int kb = 0; kb < 4; kb++) bfr[kb] = sb8[(t*4+kb)*64 + lane];
      int h = t >> 1;
      #pragma unroll
      for (int tl = 0; tl < 2; tl++){
        if (!(tl ? act1 : act0)) continue;
        f32x4 v = {0.f,0.f,0.f,0.f};
        #pragma unroll
        for (int kb = 0; kb < 4; kb++) v = mfma16(a2[tl][kb], bfr[kb], v);
        const float* aw = attw_w + tl*320 + (r*4+h)*16;
        #pragma unroll
        for (int i = 0; i < 4; i++) zacc[tl][t][i] += aw[quad*4+i] * v[i];
      }
    }
  }

  // ---------------- residual + LN1 (registers, no LDS) ----------------
  float mu[2][4], rs[2][4];
  #pragma unroll
  for (int tl = 0; tl < 2; tl++){
    if (!(tl ? act1 : act0)) continue;
    int rowb = n0 + tl*16;
    #pragma unroll
    for (int t = 0; t < 8; t++)
      #pragma unroll
      for (int i = 0; i < 4; i++)
        zacc[tl][t][i] += ldf(xraw, (size_t)(rowb + quad*4 + i)*128 + t*16 + m, is32);
    float s1[4] = {0,0,0,0}, s2[4] = {0,0,0,0};
    #pragma unroll
    for (int t = 0; t < 8; t++)
      #pragma unroll
      for (int i = 0; i < 4; i++){ float y = zacc[tl][t][i]; s1[i] += y; s2[i] += y*y; }
    #pragma unroll
    for (int mask = 1; mask < 16; mask <<= 1){
      #pragma unroll
      for (int i = 0; i < 4; i++){
        s1[i] += __shfl_xor(s1[i], mask, 16);
        s2[i] += __shfl_xor(s2[i], mask, 16);
      }
    }
    #pragma unroll
    for (int i = 0; i < 4; i++){
      mu[tl][i] = s1[i] * (1.f/128.f);
      float var = s2[i] * (1.f/128.f) - mu[tl][i]*mu[tl][i];
      rs[tl][i] = rsqrtf(var + 1e-5f);
    }
  }

  // h = LN1(...) : write per-32-col sub-chunk into per-wave scratch, pull A-frags.
  // attw_w is dead; pws_w overlays it (same wave slice -> no barrier).
  unsigned int hDp[2][8][2];
  short8 ah[2][4];
  #pragma unroll
  for (int kb = 0; kb < 4; kb++){
    #pragma unroll
    for (int u = 0; u < 2; u++){
      int t = kb*2 + u;
      #pragma unroll
      for (int tl = 0; tl < 2; tl++){
        if (!(tl ? act1 : act0)) continue;
        float gg = b2f(g1s[t*16+m]), bb = b2f(be1s[t*16+m]);
        u16 hv[4];
        #pragma unroll
        for (int i = 0; i < 4; i++){
          hv[i] = f2b((zacc[tl][t][i]-mu[tl][i])*rs[tl][i]*gg + bb);
          pws_w[(tl*16 + quad*4 + i)*PWS_PITCH + u*16 + m] = hv[i];
        }
        hDp[tl][t][0] = (unsigned int)hv[0] | ((unsigned int)hv[1] << 16);
        hDp[tl][t][1] = (unsigned int)hv[2] | ((unsigned int)hv[3] << 16);
      }
    }
    #pragma unroll
    for (int tl = 0; tl < 2; tl++)
      ah[tl][kb] = lds_afrag(pws_w + (tl*16 + m)*PWS_PITCH + quad*8);
  }

  // ---------------- FFN ----------------
  f32x4 f2acc[2][8];
  #pragma unroll
  for (int tl = 0; tl < 2; tl++)
    #pragma unroll
    for (int t = 0; t < 8; t++) f2acc[tl][t] = (f32x4){0.f,0.f,0.f,0.f};

  for (int c = 0; c < 4; c++){
    for (int kp = 0; kp < 2; kp++){
      __syncthreads();
      for (int s = tid; s < 2048; s += 256)
        ((short8*)sbuf)[s] =
            ((const short8*)(pw + OFF_W1 + (size_t)(c*4 + kp*2)*8192))[s];
      __syncthreads();
      #pragma unroll
      for (int kb2w = 0; kb2w < 2; kb2w++){
        int kb2 = kp*2 + kb2w;
        const short8* w1f = sb8 + kb2w*1024;
        const short8* w2f = w1f + 512;
        // G sub-chunk (32 dff cols) -> per-wave scratch
        #pragma unroll
        for (int u = 0; u < 2; u++){
          short8 bfr[4];
          #pragma unroll
          for (int kb = 0; kb < 4; kb++) bfr[kb] = w1f[(u*4+kb)*64 + lane];
          float b1c = b2f(b1s[c*128 + (kb2*2+u)*16 + m]);
          #pragma unroll
          for (int tl = 0; tl < 2; tl++){
            if (!(tl ? act1 : act0)) continue;
            f32x4 g = {0.f,0.f,0.f,0.f};
            #pragma unroll
            for (int kb = 0; kb < 4; kb++) g = mfma16(ah[tl][kb], bfr[kb], g);
            #pragma unroll
            for (int i = 0; i < 4; i++)
              pws_w[(tl*16 + quad*4 + i)*PWS_PITCH + u*16 + m]
                  = f2b(fmaxf(g[i] + b1c, 0.f));
          }
        }
        short8 ag[2];
        #pragma unroll
        for (int tl = 0; tl < 2; tl++)
          ag[tl] = lds_afrag(pws_w + (tl*16 + m)*PWS_PITCH + quad*8);
        #pragma unroll
        for (int t = 0; t < 8; t++){
          short8 bf = w2f[t*64 + lane];
          #pragma unroll
          for (int tl = 0; tl < 2; tl++){
            if (!(tl ? act1 : act0)) continue;
            f2acc[tl][t] = mfma16(ag[tl], bf, f2acc[tl][t]);
          }
        }
      }
    }
  }

  // ---------------- residual 2 + LN2 + fp32 store ----------------
  #pragma unroll
  for (int tl = 0; tl < 2; tl++){
    if (!(tl ? act1 : act0)) continue;
    int rowb = n0 + tl*16;
    #pragma unroll
    for (int t = 0; t < 8; t++){
      float b2c = b2f(b2s[t*16 + m]);
      f2acc[tl][t][0] += b2f((u16)(hDp[tl][t][0] & 0xffff)) + b2c;
      f2acc[tl][t][1] += b2f((u16)(hDp[tl][t][0] >> 16))    + b2c;
      f2acc[tl][t][2] += b2f((u16)(hDp[tl][t][1] & 0xffff)) + b2c;
      f2acc[tl][t][3] += b2f((u16)(hDp[tl][t][1] >> 16))    + b2c;
    }
    float s1[4] = {0,0,0,0}, s2[4] = {0,0,0,0};
    #pragma unroll
    for (int t = 0; t < 8; t++)
      #pragma unroll
      for (int i = 0; i < 4; i++){ float y = f2acc[tl][t][i]; s1[i] += y; s2[i] += y*y; }
    #pragma unroll
    for (int mask = 1; mask < 16; mask <<= 1){
      #pragma unroll
      for (int i = 0; i < 4; i++){
        s1[i] += __shfl_xor(s1[i], mask, 16);
        s2[i] += __shfl_xor(s2[i], mask, 16);
      }
    }
    float mu2[4], rs2[4];
    #pragma unroll
    for (int i = 0; i < 4; i++){
      mu2[i] = s1[i] * (1.f/128.f);
      float var = s2[i] * (1.f/128.f) - mu2[i]*mu2[i];
      rs2[i] = rsqrtf(var + 1e-5f);
    }
    #pragma unroll
    for (int t = 0; t < 8; t++){
      float gg = b2f(g2s[t*16+m]), bb = b2f(be2s[t*16+m]);
      #pragma unroll
      for (int i = 0; i < 4; i++)
        out[(size_t)(rowb + quad*4 + i)*128 + t*16 + m] =
            (f2acc[tl][t][i]-mu2[i])*rs2[i]*gg + bb;
    }
  }
}

extern "C" void kernel_launch(void* const* d_in, const int* in_sizes, int n_in,
                              void* d_out, int out_size, void* d_ws, size_t ws_size,
                              hipStream_t stream)
{
  const void* x   = d_in[0];
  const int*  nbr = (const int*)d_in[1];
  const void* wq  = d_in[2];
  const void* wk  = d_in[3];
  const void* wv  = d_in[4];
  const void* W1  = d_in[5];
  const void* b1  = d_in[6];
  const void* W2  = d_in[7];
  const void* b2  = d_in[8];
  const void* g1  = d_in[9];
  const void* be1 = d_in[10];
  const void* g2  = d_in[11];
  const void* be2 = d_in[12];
  float* out = (float*)d_out;

  char* ws = (char*)d_ws;
  float* lws  = (float*)(ws + WS_LWS);
  float* pm   = (float*)(ws + WS_PM);
  float* ps   = (float*)(ws + WS_PS);
  float* mhr  = (float*)(ws + WS_MHR);
  float* ishr = (float*)(ws + WS_ISHR);
  u16*   pk   = (u16*)  (ws + WS_PK);
  u16*   xb   = (u16*)  (ws + WS_XB);
  u16*   sv   = (u16*)  (ws + WS_SV);

  k_convert_x<<<dim3(12500), dim3(256), 0, stream>>>(x, g1, xb);
  k_convert_small<<<dim3(1), dim3(256), 0, stream>>>(b1, b2, g1, be1, g2, be2, sv);
  k_pack<<<dim3((PACK_ELEMS+255)/256), dim3(256), 0, stream>>>(wq, wk, wv, W1, W2, g1, pk);
  k_qk<<<dim3((NN+127)/128), dim3(256), 0, stream>>>(xb, nbr, pk, lws);
  k_red_part<<<dim3(160), dim3(256), 0, stream>>>(lws, pm, ps);
  k_red_fin<<<dim3(1), dim3(64), 0, stream>>>(pm, ps, mhr, ishr);
  k_attn_ffn<<<dim3((NN+127)/128), dim3(256), 0, stream>>>(xb, x, nbr, pk, lws, mhr, ishr,
                                                           sv, g1, out);
}

// Round 6
// 302.681 us; speedup vs baseline: 1.1667x; 1.1667x over previous
//
#include <hip/hip_runtime.h>
#include <hip/hip_bf16.h>

typedef unsigned short u16;
typedef __attribute__((ext_vector_type(8))) short short8;
typedef __attribute__((ext_vector_type(4))) float f32x4;
typedef __attribute__((ext_vector_type(4))) float float4v;
typedef __attribute__((ext_vector_type(4))) unsigned short us4;
typedef __attribute__((ext_vector_type(4))) int int4v;

#define NN       100000
#define OFF_WK   16384
#define OFF_WV   98304
#define OFF_W1   180224     // combined W1/W2 region: [c][kb2][W1 4096 u16][W2 4096 u16]
#define PACK_ELEMS 311296

// ws byte offsets
#define WS_LWS   0u
#define WS_PM    8000000u
#define WS_PS    8000640u
#define WS_MHR   8001280u
#define WS_ISHR  8001408u
#define WS_PK    8001536u
#define WS_XB    8624128u          // 12.8M u16 = 25,600,000 B
#define WS_SV    34224128u         // 1152 u16 small vectors

// per-wave LDS scratch: 32 rows x pitch 40 u16 (80 B rows: 16B-aligned, <=2-way banks)
#define PWS_PITCH 40
#define PWS_SLICE 1280             // u16 per wave = 2560 B (32*40 exactly); == 640 floats (attw overlay)

static __device__ __forceinline__ float b2f(u16 u){
  unsigned int i = ((unsigned int)u) << 16;
  float f; __builtin_memcpy(&f, &i, 4); return f;
}
static __device__ __forceinline__ u16 f2b(float f){
  unsigned int i; __builtin_memcpy(&i, &f, 4);
  i += 0x7FFFu + ((i >> 16) & 1u);
  return (u16)(i >> 16);
}
static __device__ __forceinline__ f32x4 mfma16(short8 a, short8 b, f32x4 c){
  return __builtin_amdgcn_mfma_f32_16x16x32_bf16(a, b, c, 0, 0, 0);
}
static __device__ __forceinline__ bool detect32(const void* g1){
  return ((const u16*)g1)[0] == 0;
}
static __device__ __forceinline__ float ldf(const void* p, size_t i, bool is32){
  return is32 ? ((const float*)p)[i] : b2f(((const u16*)p)[i]);
}

// ---------- canonicalize x to bf16 ----------
__global__ __launch_bounds__(256) void k_convert_x(
    const void* __restrict__ x, const void* __restrict__ g1, u16* __restrict__ xb)
{
  const bool is32 = detect32(g1);
  size_t i = (size_t)blockIdx.x * 256 + threadIdx.x;   // 4 elems each
  us4 o;
  if (is32){
    float4v v = ((const float4v*)x)[i];
    o.x = f2b(v.x); o.y = f2b(v.y); o.z = f2b(v.z); o.w = f2b(v.w);
  } else {
    o = ((const us4*)x)[i];
  }
  ((us4*)xb)[i] = o;
}

// ---------- canonicalize small vectors ----------
__global__ __launch_bounds__(256) void k_convert_small(
    const void* b1, const void* b2, const void* g1, const void* be1,
    const void* g2, const void* be2, u16* __restrict__ sv)
{
  const bool is32 = detect32(g1);
  for (int i = threadIdx.x; i < 1152; i += 256){
    const void* src; int off;
    if      (i < 512) { src = b1;  off = i; }
    else if (i < 640) { src = b2;  off = i - 512; }
    else if (i < 768) { src = g1;  off = i - 640; }
    else if (i < 896) { src = be1; off = i - 768; }
    else if (i < 1024){ src = g2;  off = i - 896; }
    else              { src = be2; off = i - 1024; }
    sv[i] = f2b(ldf(src, off, is32));
  }
}

// ---------- weight repack into MFMA-B-fragment order ----------
__global__ __launch_bounds__(256) void k_pack(
    const void* __restrict__ wq, const void* __restrict__ wk,
    const void* __restrict__ wv, const void* __restrict__ W1,
    const void* __restrict__ W2, const void* __restrict__ g1,
    u16* __restrict__ pk)
{
  const bool is32 = detect32(g1);
  int p = blockIdx.x * 256 + threadIdx.x;
  if (p >= PACK_ELEMS) return;
  float v;
  if (p < OFF_WK){                       // Wq
    int q = p;
    int j = q & 7, lane = (q >> 3) & 63, tk = q >> 9;
    int kb = tk & 3, t = tk >> 2;
    int kd = kb*32 + (lane>>4)*8 + j, nc = t*16 + (lane & 15);
    v = ldf(wq, (size_t)(nc>>5)*4096 + kd*32 + (nc & 31), is32);
  } else if (p < OFF_WV){                // Wk[r]
    int q = p - OFF_WK; int r = q >> 14; q &= 16383;
    int j = q & 7, lane = (q >> 3) & 63, tk = q >> 9;
    int kb = tk & 3, t = tk >> 2;
    int kd = kb*32 + (lane>>4)*8 + j, nc = t*16 + (lane & 15);
    v = ldf(wk, (size_t)((nc>>5)*5 + r)*4096 + kd*32 + (nc & 31), is32);
  } else if (p < OFF_W1){                // Wv[r]
    int q = p - OFF_WV; int r = q >> 14; q &= 16383;
    int j = q & 7, lane = (q >> 3) & 63, tk = q >> 9;
    int kb = tk & 3, t = tk >> 2;
    int kd = kb*32 + (lane>>4)*8 + j, nc = t*16 + (lane & 15);
    v = ldf(wv, (size_t)((nc>>5)*5 + r)*4096 + kd*32 + (nc & 31), is32);
  } else {                               // W1/W2 interleaved per (c,kb2)
    int q = p - OFF_W1;
    int j = q & 7, lane = (q >> 3) & 63, rest = q >> 9;   // [0,256)
    int pairIdx = rest >> 4, sub = rest & 15;
    int c = pairIdx >> 2, kb2 = pairIdx & 3;
    int half = lane >> 4, mc = lane & 15;
    if (sub < 8){                        // W1 frag [u][kb]
      int u = sub >> 2, kb = sub & 3;
      int kd = kb*32 + half*8 + j;
      int nc = c*128 + (kb2*2+u)*16 + mc;
      v = ldf(W1, (size_t)kd*512 + nc, is32);
    } else {                             // W2 frag [t]
      int t = sub - 8;
      int kd = (c*4+kb2)*32 + half*8 + j;
      int nc = t*16 + mc;
      v = ldf(W2, (size_t)kd*128 + nc, is32);
    }
  }
  pk[p] = f2b(v);
}

// ---------- phase 1: Q, K, logits — dbuf weights + gather prefetch ----------
__global__ __launch_bounds__(256, 2) void k_qk(
    const u16* __restrict__ x, const int* __restrict__ nbr,
    const u16* __restrict__ pw, float* __restrict__ lws)
{
  __shared__ __align__(16) u16 sbuf[32768];   // 2 x 32 KB weight stage
  const int tid = threadIdx.x, lane = tid & 63, wv = tid >> 6;
  const int m = lane & 15, quad = lane >> 4;
  const int n0 = blockIdx.x * 128 + wv * 32;
  const bool act0 = (n0 < NN), act1 = (n0 + 16 < NN);
  short8* sb = (short8*)sbuf;
  const short8* wq8 = (const short8*)pw;
  const short8* wk8 = (const short8*)(pw + OFF_WK);

  // neighbor indices + self A-frags (issued early)
  int nd[2][4];
  short8 a2[2][4], a2n[2][4];
  #pragma unroll
  for (int tl = 0; tl < 2; tl++){
    if (!(tl ? act1 : act0)) continue;
    int4v t4 = *(const int4v*)(nbr + (size_t)(n0 + tl*16 + m)*4);
    nd[tl][0]=t4.x; nd[tl][1]=t4.y; nd[tl][2]=t4.z; nd[tl][3]=t4.w;
    const short8* xp = (const short8*)(x + (size_t)(n0 + tl*16 + m) * 128);
    #pragma unroll
    for (int kb = 0; kb < 4; kb++) a2[tl][kb] = xp[kb*4 + quad];
  }

  // stage Wq -> buf0
  short8 wreg[8];
  #pragma unroll
  for (int k = 0; k < 8; k++) wreg[k] = wq8[tid + k*256];
  #pragma unroll
  for (int k = 0; k < 8; k++) sb[tid + k*256] = wreg[k];
  __syncthreads();

  // Q accumulate from buf0; meanwhile prefetch Wk0
  #pragma unroll
  for (int k = 0; k < 8; k++) wreg[k] = wk8[tid + k*256];
  f32x4 q[2][8];
  #pragma unroll
  for (int tl = 0; tl < 2; tl++)
    #pragma unroll
    for (int t = 0; t < 8; t++) q[tl][t] = (f32x4){0.f,0.f,0.f,0.f};
  #pragma unroll
  for (int t = 0; t < 8; t++){
    short8 bfr[4];
    #pragma unroll
    for (int kb = 0; kb < 4; kb++) bfr[kb] = sb[(t*4+kb)*64 + lane];
    #pragma unroll
    for (int tl = 0; tl < 2; tl++){
      if (!(tl ? act1 : act0)) continue;
      #pragma unroll
      for (int kb = 0; kb < 4; kb++) q[tl][t] = mfma16(a2[tl][kb], bfr[kb], q[tl][t]);
    }
  }
  {
    short8* nxt = (short8*)(sbuf + 16384);
    #pragma unroll
    for (int k = 0; k < 8; k++) nxt[tid + k*256] = wreg[k];
  }
  __syncthreads();

  // rounds: Wk_r lives in buf[(r+1)&1]
  for (int r = 0; r < 5; r++){
    const short8* cur = (const short8*)(sbuf + ((r+1)&1)*16384);
    if (r < 4){
      #pragma unroll
      for (int k = 0; k < 8; k++) wreg[k] = wk8[(r+1)*2048 + tid + k*256];
      #pragma unroll
      for (int tl = 0; tl < 2; tl++){
        if (!(tl ? act1 : act0)) continue;
        const short8* gp = (const short8*)(x + (size_t)nd[tl][r] * 128);
        #pragma unroll
        for (int kb = 0; kb < 4; kb++) a2n[tl][kb] = gp[kb*4 + quad];
      }
    }
    #pragma unroll
    for (int h = 0; h < 4; h++){
      short8 b0[4], b1f[4];
      #pragma unroll
      for (int kb = 0; kb < 4; kb++){
        b0[kb]  = cur[((2*h  )*4+kb)*64 + lane];
        b1f[kb] = cur[((2*h+1)*4+kb)*64 + lane];
      }
      #pragma unroll
      for (int tl = 0; tl < 2; tl++){
        if (!(tl ? act1 : act0)) continue;
        f32x4 k0 = {0.f,0.f,0.f,0.f}, k1 = {0.f,0.f,0.f,0.f};
        #pragma unroll
        for (int kb = 0; kb < 4; kb++){
          k0 = mfma16(a2[tl][kb], b0[kb],  k0);
          k1 = mfma16(a2[tl][kb], b1f[kb], k1);
        }
        float p[4];
        #pragma unroll
        for (int i = 0; i < 4; i++) p[i] = q[tl][2*h][i]*k0[i] + q[tl][2*h+1][i]*k1[i];
        #pragma unroll
        for (int mask = 1; mask < 16; mask <<= 1){
          #pragma unroll
          for (int i = 0; i < 4; i++) p[i] += __shfl_xor(p[i], mask, 16);
        }
        if (m == 0){
          #pragma unroll
          for (int i = 0; i < 4; i++)
            lws[(size_t)(h*5+r)*NN + n0 + tl*16 + quad*4 + i]
                = p[i] * 0.17677669529663687f;
        }
      }
    }
    if (r < 4){
      short8* nxt = (short8*)(sbuf + (r&1)*16384);
      #pragma unroll
      for (int k = 0; k < 8; k++) nxt[tid + k*256] = wreg[k];
      #pragma unroll
      for (int tl = 0; tl < 2; tl++)
        #pragma unroll
        for (int kb = 0; kb < 4; kb++) a2[tl][kb] = a2n[tl][kb];
    }
    __syncthreads();
  }
}

// ---------- phase 2a: per-(h,r) partial max / sumexp ----------
__global__ __launch_bounds__(256) void k_red_part(
    const float* __restrict__ lws, float* __restrict__ pm, float* __restrict__ ps)
{
  const int hr = blockIdx.x >> 3, pb = blockIdx.x & 7;
  const int start = pb * 12500, end = start + 12500;
  const float* v = lws + (size_t)hr * NN;
  __shared__ float red[256];
  float mx = -1e30f;
  for (int i = start + threadIdx.x; i < end; i += 256) mx = fmaxf(mx, v[i]);
  red[threadIdx.x] = mx; __syncthreads();
  for (int s = 128; s > 0; s >>= 1){
    if ((int)threadIdx.x < s) red[threadIdx.x] = fmaxf(red[threadIdx.x], red[threadIdx.x+s]);
    __syncthreads();
  }
  mx = red[0]; __syncthreads();
  float sm = 0.f;
  for (int i = start + threadIdx.x; i < end; i += 256) sm += __expf(v[i] - mx);
  red[threadIdx.x] = sm; __syncthreads();
  for (int s = 128; s > 0; s >>= 1){
    if ((int)threadIdx.x < s) red[threadIdx.x] += red[threadIdx.x+s];
    __syncthreads();
  }
  if (threadIdx.x == 0){ pm[blockIdx.x] = mx; ps[blockIdx.x] = red[0]; }
}

__global__ __launch_bounds__(64) void k_red_fin(
    const float* __restrict__ pm, const float* __restrict__ ps,
    float* __restrict__ mhr, float* __restrict__ ishr)
{
  int t = threadIdx.x;
  if (t < 20){
    float M = -1e30f;
    for (int b = 0; b < 8; b++) M = fmaxf(M, pm[t*8+b]);
    float S = 0.f;
    for (int b = 0; b < 8; b++) S += ps[t*8+b] * __expf(pm[t*8+b] - M);
    mhr[t] = M; ishr[t] = 1.0f / S;
  }
}

// ---------- phase 3: V, combine, LN1, FFN, LN2 — dbuf weights + gather prefetch ----
__global__ __launch_bounds__(256, 2) void k_attn_ffn(
    const u16* __restrict__ x, const void* __restrict__ xraw,
    const int* __restrict__ nbr,
    const u16* __restrict__ pw, const float* __restrict__ lws,
    const float* __restrict__ mhr, const float* __restrict__ ishr,
    const u16* __restrict__ sv, const void* __restrict__ g1raw,
    float* __restrict__ out)
{
  __shared__ __align__(16) u16 sbuf[32768];    // 2 x 32 KB weight stage
  __shared__ __align__(16) u16 upool[5120];    // 10 KB: per-wave attw (V) / pws (FFN)
  const int tid = threadIdx.x, lane = tid & 63, wv = tid >> 6;
  const int m = lane & 15, quad = lane >> 4;
  const int n0 = blockIdx.x * 128 + wv * 32;
  const bool act0 = (n0 < NN), act1 = (n0 + 16 < NN);
  const bool is32 = detect32(g1raw);
  const u16* b1s = sv;
  const u16* b2s = sv + 512;
  const u16* g1s = sv + 640;
  const u16* be1s = sv + 768;
  const u16* g2s = sv + 896;
  const u16* be2s = sv + 1024;
  short8* sb = (short8*)sbuf;
  const short8* wv8 = (const short8*)(pw + OFF_WV);
  const short8* wf8 = (const short8*)(pw + OFF_W1);
  float* attw_w = ((float*)upool) + wv * 640;
  u16*   pws_w  = upool + wv * PWS_SLICE;

  // per-wave attention weights (issued early; high-latency lws reads)
  for (int j = lane; j < 640; j += 64){
    int tl = j / 320, rem = j - tl*320;
    int r = rem >> 6, h = (rem >> 4) & 3, mm = rem & 15, hr = h*5 + r;
    int node = n0 + tl*16 + mm;
    attw_w[j] = (node < NN)
        ? __expf(lws[(size_t)hr*NN + node] - mhr[hr]) * ishr[hr] : 0.f;
  }

  // neighbor indices + self A-frags
  int nd[2][4];
  short8 a2[2][4], a2n[2][4];
  #pragma unroll
  for (int tl = 0; tl < 2; tl++){
    if (!(tl ? act1 : act0)) continue;
    int4v t4 = *(const int4v*)(nbr + (size_t)(n0 + tl*16 + m)*4);
    nd[tl][0]=t4.x; nd[tl][1]=t4.y; nd[tl][2]=t4.z; nd[tl][3]=t4.w;
    const short8* xp = (const short8*)(x + (size_t)(n0 + tl*16 + m) * 128);
    #pragma unroll
    for (int kb = 0; kb < 4; kb++) a2[tl][kb] = xp[kb*4 + quad];
  }

  // stage Wv0 -> buf0
  short8 wreg[8];
  #pragma unroll
  for (int k = 0; k < 8; k++) wreg[k] = wv8[tid + k*256];
  #pragma unroll
  for (int k = 0; k < 8; k++) sb[tid + k*256] = wreg[k];
  __syncthreads();

  // ---------------- V phase (pipelined) ----------------
  f32x4 zacc[2][8];
  #pragma unroll
  for (int tl = 0; tl < 2; tl++)
    #pragma unroll
    for (int t = 0; t < 8; t++) zacc[tl][t] = (f32x4){0.f,0.f,0.f,0.f};

  for (int r = 0; r < 5; r++){
    const short8* cur = (const short8*)(sbuf + (r&1)*16384);
    if (r < 4){
      #pragma unroll
      for (int k = 0; k < 8; k++) wreg[k] = wv8[(r+1)*2048 + tid + k*256];
      #pragma unroll
      for (int tl = 0; tl < 2; tl++){
        if (!(tl ? act1 : act0)) continue;
        const short8* gp = (const short8*)(x + (size_t)nd[tl][r] * 128);
        #pragma unroll
        for (int kb = 0; kb < 4; kb++) a2n[tl][kb] = gp[kb*4 + quad];
      }
    }
    #pragma unroll
    for (int t = 0; t < 8; t++){
      short8 bfr[4];
      #pragma unroll
      for (int kb = 0; kb < 4; kb++) bfr[kb] = cur[(t*4+kb)*64 + lane];
      int h = t >> 1;
      #pragma unroll
      for (int tl = 0; tl < 2; tl++){
        if (!(tl ? act1 : act0)) continue;
        f32x4 v = {0.f,0.f,0.f,0.f};
        #pragma unroll
        for (int kb = 0; kb < 4; kb++) v = mfma16(a2[tl][kb], bfr[kb], v);
        const float* aw = attw_w + tl*320 + (r*4+h)*16;
        #pragma unroll
        for (int i = 0; i < 4; i++) zacc[tl][t][i] += aw[quad*4+i] * v[i];
      }
    }
    if (r < 4){
      short8* nxt = (short8*)(sbuf + ((r+1)&1)*16384);
      #pragma unroll
      for (int k = 0; k < 8; k++) nxt[tid + k*256] = wreg[k];
      #pragma unroll
      for (int tl = 0; tl < 2; tl++)
        #pragma unroll
        for (int kb = 0; kb < 4; kb++) a2[tl][kb] = a2n[tl][kb];
    }
    __syncthreads();
  }

  // prefetch FFN stage 0 while LN1 runs
  #pragma unroll
  for (int k = 0; k < 8; k++) wreg[k] = wf8[tid + k*256];

  // ---------------- residual + LN1 (registers) ----------------
  float mu[2][4], rs[2][4];
  #pragma unroll
  for (int tl = 0; tl < 2; tl++){
    if (!(tl ? act1 : act0)) continue;
    int rowb = n0 + tl*16;
    #pragma unroll
    for (int t = 0; t < 8; t++)
      #pragma unroll
      for (int i = 0; i < 4; i++)
        zacc[tl][t][i] += ldf(xraw, (size_t)(rowb + quad*4 + i)*128 + t*16 + m, is32);
    float s1[4] = {0,0,0,0}, s2[4] = {0,0,0,0};
    #pragma unroll
    for (int t = 0; t < 8; t++)
      #pragma unroll
      for (int i = 0; i < 4; i++){ float y = zacc[tl][t][i]; s1[i] += y; s2[i] += y*y; }
    #pragma unroll
    for (int mask = 1; mask < 16; mask <<= 1){
      #pragma unroll
      for (int i = 0; i < 4; i++){
        s1[i] += __shfl_xor(s1[i], mask, 16);
        s2[i] += __shfl_xor(s2[i], mask, 16);
      }
    }
    #pragma unroll
    for (int i = 0; i < 4; i++){
      mu[tl][i] = s1[i] * (1.f/128.f);
      float var = s2[i] * (1.f/128.f) - mu[tl][i]*mu[tl][i];
      rs[tl][i] = rsqrtf(var + 1e-5f);
    }
  }

  // h = LN1(...): per-32-col sub-chunks through per-wave scratch -> A-frags
  unsigned int hDp[2][8][2];
  short8 ah[2][4];
  #pragma unroll
  for (int kb = 0; kb < 4; kb++){
    #pragma unroll
    for (int u = 0; u < 2; u++){
      int t = kb*2 + u;
      #pragma unroll
      for (int tl = 0; tl < 2; tl++){
        if (!(tl ? act1 : act0)) continue;
        float gg = b2f(g1s[t*16+m]), bb = b2f(be1s[t*16+m]);
        u16 hv[4];
        #pragma unroll
        for (int i = 0; i < 4; i++){
          hv[i] = f2b((zacc[tl][t][i]-mu[tl][i])*rs[tl][i]*gg + bb);
          pws_w[(tl*16 + quad*4 + i)*PWS_PITCH + u*16 + m] = hv[i];
        }
        hDp[tl][t][0] = (unsigned int)hv[0] | ((unsigned int)hv[1] << 16);
        hDp[tl][t][1] = (unsigned int)hv[2] | ((unsigned int)hv[3] << 16);
      }
    }
    #pragma unroll
    for (int tl = 0; tl < 2; tl++)
      ah[tl][kb] = *(const short8*)(pws_w + (tl*16 + m)*PWS_PITCH + quad*8);
  }

  // store FFN stage 0 -> buf0
  #pragma unroll
  for (int k = 0; k < 8; k++) sb[tid + k*256] = wreg[k];
  __syncthreads();

  // ---------------- FFN (pipelined, 8 stages) ----------------
  f32x4 f2acc[2][8];
  #pragma unroll
  for (int tl = 0; tl < 2; tl++)
    #pragma unroll
    for (int t = 0; t < 8; t++) f2acc[tl][t] = (f32x4){0.f,0.f,0.f,0.f};

  for (int s = 0; s < 8; s++){
    const short8* cur = (const short8*)(sbuf + (s&1)*16384);
    const int c = s >> 1, kp = s & 1;
    if (s < 7){
      #pragma unroll
      for (int k = 0; k < 8; k++) wreg[k] = wf8[(s+1)*2048 + tid + k*256];
    }
    #pragma unroll
    for (int kb2w = 0; kb2w < 2; kb2w++){
      int kb2 = kp*2 + kb2w;
      const short8* w1f = cur + kb2w*1024;
      const short8* w2f = w1f + 512;
      #pragma unroll
      for (int u = 0; u < 2; u++){
        short8 bfr[4];
        #pragma unroll
        for (int kb = 0; kb < 4; kb++) bfr[kb] = w1f[(u*4+kb)*64 + lane];
        float b1c = b2f(b1s[c*128 + (kb2*2+u)*16 + m]);
        #pragma unroll
        for (int tl = 0; tl < 2; tl++){
          if (!(tl ? act1 : act0)) continue;
          f32x4 g = {0.f,0.f,0.f,0.f};
          #pragma unroll
          for (int kb = 0; kb < 4; kb++) g = mfma16(ah[tl][kb], bfr[kb], g);
          #pragma unroll
          for (int i = 0; i < 4; i++)
            pws_w[(tl*16 + quad*4 + i)*PWS_PITCH + u*16 + m]
                = f2b(fmaxf(g[i] + b1c, 0.f));
        }
      }
      short8 ag[2];
      #pragma unroll
      for (int tl = 0; tl < 2; tl++)
        ag[tl] = *(const short8*)(pws_w + (tl*16 + m)*PWS_PITCH + quad*8);
      #pragma unroll
      for (int t = 0; t < 8; t++){
        short8 bf = w2f[t*64 + lane];
        #pragma unroll
        for (int tl = 0; tl < 2; tl++){
          if (!(tl ? act1 : act0)) continue;
          f2acc[tl][t] = mfma16(ag[tl], bf, f2acc[tl][t]);
        }
      }
    }
    if (s < 7){
      short8* nxt = (short8*)(sbuf + ((s+1)&1)*16384);
      #pragma unroll
      for (int k = 0; k < 8; k++) nxt[tid + k*256] = wreg[k];
    }
    __syncthreads();
  }

  // ---------------- residual 2 + LN2 + fp32 store ----------------
  #pragma unroll
  for (int tl = 0; tl < 2; tl++){
    if (!(tl ? act1 : act0)) continue;
    int rowb = n0 + tl*16;
    #pragma unroll
    for (int t = 0; t < 8; t++){
      float b2c = b2f(b2s[t*16 + m]);
      f2acc[tl][t][0] += b2f((u16)(hDp[tl][t][0] & 0xffff)) + b2c;
      f2acc[tl][t][1] += b2f((u16)(hDp[tl][t][0] >> 16))    + b2c;
      f2acc[tl][t][2] += b2f((u16)(hDp[tl][t][1] & 0xffff)) + b2c;
      f2acc[tl][t][3] += b2f((u16)(hDp[tl][t][1] >> 16))    + b2c;
    }
    float s1[4] = {0,0,0,0}, s2[4] = {0,0,0,0};
    #pragma unroll
    for (int t = 0; t < 8; t++)
      #pragma unroll
      for (int i = 0; i < 4; i++){ float y = f2acc[tl][t][i]; s1[i] += y; s2[i] += y*y; }
    #pragma unroll
    for (int mask = 1; mask < 16; mask <<= 1){
      #pragma unroll
      for (int i = 0; i < 4; i++){
        s1[i] += __shfl_xor(s1[i], mask, 16);
        s2[i] += __shfl_xor(s2[i], mask, 16);
      }
    }
    float mu2[4], rs2[4];
    #pragma unroll
    for (int i = 0; i < 4; i++){
      mu2[i] = s1[i] * (1.f/128.f);
      float var = s2[i] * (1.f/128.f) - mu2[i]*mu2[i];
      rs2[i] = rsqrtf(var + 1e-5f);
    }
    #pragma unroll
    for (int t = 0; t < 8; t++){
      float gg = b2f(g2s[t*16+m]), bb = b2f(be2s[t*16+m]);
      #pragma unroll
      for (int i = 0; i < 4; i++)
        out[(size_t)(rowb + quad*4 + i)*128 + t*16 + m] =
            (f2acc[tl][t][i]-mu2[i])*rs2[i]*gg + bb;
    }
  }
}

extern "C" void kernel_launch(void* const* d_in, const int* in_sizes, int n_in,
                              void* d_out, int out_size, void* d_ws, size_t ws_size,
                              hipStream_t stream)
{
  const void* x   = d_in[0];
  const int*  nbr = (const int*)d_in[1];
  const void* wq  = d_in[2];
  const void* wk  = d_in[3];
  const void* wv  = d_in[4];
  const void* W1  = d_in[5];
  const void* b1  = d_in[6];
  const void* W2  = d_in[7];
  const void* b2  = d_in[8];
  const void* g1  = d_in[9];
  const void* be1 = d_in[10];
  const void* g2  = d_in[11];
  const void* be2 = d_in[12];
  float* out = (float*)d_out;

  char* ws = (char*)d_ws;
  float* lws  = (float*)(ws + WS_LWS);
  float* pm   = (float*)(ws + WS_PM);
  float* ps   = (float*)(ws + WS_PS);
  float* mhr  = (float*)(ws + WS_MHR);
  float* ishr = (float*)(ws + WS_ISHR);
  u16*   pk   = (u16*)  (ws + WS_PK);
  u16*   xb   = (u16*)  (ws + WS_XB);
  u16*   sv   = (u16*)  (ws + WS_SV);

  k_convert_x<<<dim3(12500), dim3(256), 0, stream>>>(x, g1, xb);
  k_convert_small<<<dim3(1), dim3(256), 0, stream>>>(b1, b2, g1, be1, g2, be2, sv);
  k_pack<<<dim3((PACK_ELEMS+255)/256), dim3(256), 0, stream>>>(wq, wk, wv, W1, W2, g1, pk);
  k_qk<<<dim3((NN+127)/128), dim3(256), 0, stream>>>(xb, nbr, pk, lws);
  k_red_part<<<dim3(160), dim3(256), 0, stream>>>(lws, pm, ps);
  k_red_fin<<<dim3(1), dim3(64), 0, stream>>>(pm, ps, mhr, ishr);
  k_attn_ffn<<<dim3((NN+127)/128), dim3(256), 0, stream>>>(xb, x, nbr, pk, lws, mhr, ishr,
                                                           sv, g1, out);
}